// Round 1
// baseline (303.213 us; speedup 1.0000x reference)
//
#include <hip/hip_runtime.h>

// Problem: B=1, L=4096, EMBED=1024, 16 heads x 64
static constexpr int L_SEQ = 4096;
static constexpr int EMBED = 1024;
static constexpr int HEADS = 16;
static constexpr int HD    = 64;

typedef __attribute__((ext_vector_type(8))) short short8;   // 8 x bf16 (4 VGPR)
typedef __attribute__((ext_vector_type(4))) float f32x4;

#define LOG2E 1.4426950408889634f

__device__ __forceinline__ unsigned short f2bf(float f) {
  unsigned u = __builtin_bit_cast(unsigned, f);
  u += 0x7fffu + ((u >> 16) & 1u);          // round-to-nearest-even
  return (unsigned short)(u >> 16);
}
__device__ __forceinline__ float bf2f(unsigned short s) {
  return __builtin_bit_cast(float, ((unsigned)s) << 16);
}

// async global->LDS, 16B/lane; LDS dest is wave-uniform base + lane*16
#define GLOAD_LDS16(g, l) \
  __builtin_amdgcn_global_load_lds((const __attribute__((address_space(1))) void*)(g), \
                                   (__attribute__((address_space(3))) void*)(l), 16, 0, 0)

// ---------------- fp32 -> bf16 cast, 8 elems/thread ----------------
__global__ void cast_bf16_k(const float* __restrict__ in, unsigned short* __restrict__ out, int n8) {
  int i = blockIdx.x * blockDim.x + threadIdx.x;
  if (i >= n8) return;
  const float4* p = (const float4*)in;
  float4 a = p[2 * i], b = p[2 * i + 1];
  uint4 o;
  o.x = (unsigned)f2bf(a.x) | ((unsigned)f2bf(a.y) << 16);
  o.y = (unsigned)f2bf(a.z) | ((unsigned)f2bf(a.w) << 16);
  o.z = (unsigned)f2bf(b.x) | ((unsigned)f2bf(b.y) << 16);
  o.w = (unsigned)f2bf(b.z) | ((unsigned)f2bf(b.w) << 16);
  ((uint4*)out)[i] = o;
}

// ---------------- log2(size) ----------------
__global__ void l2size_k(const float* __restrict__ sz, float* __restrict__ l2s, int n) {
  int i = blockIdx.x * blockDim.x + threadIdx.x;
  if (i < n) l2s[i] = __log2f(sz[i]);
}

// ---------------- GEMM: C[M,N] = A[M,K] @ B[N,K]^T + bias ----------------
// 128x128 tile, BK=64, 4 waves (2x2, each 64x64 = 4x4 fragments of 16x16).
// LDS tiles [128 rows][64 k] bf16, 128B rows; XOR-swizzled 16B slots:
// slot_in_lds = slot_global ^ (row & 7). Staged with global_load_lds (linear
// dest) by pre-swizzling the GLOBAL source slot (both-sides rule).
struct GemmArgs { const unsigned short* B; const float* bias; void* dst; int mode; };
// mode 0: Q -> bf16 [h][t][64], *0.125   mode 1: K -> bf16 [h][t][64]
// mode 2: V -> bf16 [h][64][t] (transposed)   mode 3: fp32 [m][1024]

__global__ __launch_bounds__(256, 3) void gemm_bt_k(
    const unsigned short* __restrict__ A, GemmArgs g0, GemmArgs g1, GemmArgs g2)
{
  constexpr int K = 1024;
  __shared__ __align__(16) unsigned short As[128 * 64];
  __shared__ __align__(16) unsigned short Bs[128 * 64];

  GemmArgs g = (blockIdx.y == 0) ? g0 : ((blockIdx.y == 1) ? g1 : g2);
  const unsigned short* __restrict__ Bw = g.B;

  const int tid = threadIdx.x;
  const int wv = tid >> 6, ln = tid & 63;
  const int mb = blockIdx.x & 31, nb = blockIdx.x >> 5;     // 32 x 8 blocks
  const int m0 = mb * 128, n0 = nb * 128;
  const int wr = wv >> 1, wc = wv & 1;
  const int lrow = ln & 15, lq = ln >> 4;

  const int rstg = wv * 8 + (ln >> 3);       // staging row within 32-row issue
  const int ustg = (ln & 7) ^ (ln >> 3);     // pre-swizzled source 16B slot

  f32x4 acc[4][4] = {};

  for (int kt = 0; kt < K; kt += 64) {
#pragma unroll
    for (int i = 0; i < 4; ++i) {
      int r = i * 32 + rstg;
      GLOAD_LDS16(A  + (size_t)(m0 + r) * K + kt + (ustg << 3), As + i * 2048 + wv * 512);
      GLOAD_LDS16(Bw + (size_t)(n0 + r) * K + kt + (ustg << 3), Bs + i * 2048 + wv * 512);
    }
    __syncthreads();
#pragma unroll
    for (int ks = 0; ks < 2; ++ks) {
      short8 a[4], b[4];
#pragma unroll
      for (int mi = 0; mi < 4; ++mi) {
        int ra = wr * 64 + mi * 16 + lrow;
        int u = (ks * 4 + lq) ^ (ra & 7);
        a[mi] = *(const short8*)(As + ra * 64 + (u << 3));
      }
#pragma unroll
      for (int ni = 0; ni < 4; ++ni) {
        int rb = wc * 64 + ni * 16 + lrow;
        int u = (ks * 4 + lq) ^ (rb & 7);
        b[ni] = *(const short8*)(Bs + rb * 64 + (u << 3));
      }
#pragma unroll
      for (int mi = 0; mi < 4; ++mi)
#pragma unroll
        for (int ni = 0; ni < 4; ++ni)
          acc[mi][ni] = __builtin_amdgcn_mfma_f32_16x16x32_bf16(a[mi], b[ni], acc[mi][ni], 0, 0, 0);
    }
    __syncthreads();
  }

  // epilogue; C/D layout: col = lane&15, row = (lane>>4)*4 + reg
  const int mode = g.mode;
  if (mode <= 1) {
    unsigned short* dst = (unsigned short*)g.dst;
    const float sc = (mode == 0) ? 0.125f : 1.0f;
#pragma unroll
    for (int ni = 0; ni < 4; ++ni) {
      int n = n0 + wc * 64 + ni * 16 + lrow;
      float bsv = g.bias[n];
      size_t base = ((size_t)(n >> 6) * L_SEQ) * HD + (n & 63);
#pragma unroll
      for (int mi = 0; mi < 4; ++mi)
#pragma unroll
        for (int r = 0; r < 4; ++r) {
          int m = m0 + wr * 64 + mi * 16 + lq * 4 + r;
          dst[base + (size_t)m * HD] = f2bf((acc[mi][ni][r] + bsv) * sc);
        }
    }
  } else if (mode == 2) {
    unsigned short* dst = (unsigned short*)g.dst;
#pragma unroll
    for (int ni = 0; ni < 4; ++ni) {
      int n = n0 + wc * 64 + ni * 16 + lrow;     // n == h*64+hd
      float bsv = g.bias[n];
      size_t base = (size_t)n * L_SEQ;
#pragma unroll
      for (int mi = 0; mi < 4; ++mi)
#pragma unroll
        for (int r = 0; r < 4; ++r) {
          int m = m0 + wr * 64 + mi * 16 + lq * 4 + r;
          dst[base + m] = f2bf(acc[mi][ni][r] + bsv);
        }
    }
  } else {
    float* dst = (float*)g.dst;
#pragma unroll
    for (int ni = 0; ni < 4; ++ni) {
      int n = n0 + wc * 64 + ni * 16 + lrow;
      float bsv = g.bias[n];
#pragma unroll
      for (int mi = 0; mi < 4; ++mi)
#pragma unroll
        for (int r = 0; r < 4; ++r) {
          int m = m0 + wr * 64 + mi * 16 + lq * 4 + r;
          dst[(size_t)m * EMBED + n] = acc[mi][ni][r] + bsv;
        }
    }
  }
}

// ---------------- flash attention ----------------
// block = (q-tile of 64, head). 4 waves x 16 q-rows. KV tiles of 64 staged in
// LDS ([64][64] bf16, XOR-swizzled via pre-swizzled global source). Softmax in
// base-2 with log2(size) bias; P transposed through per-wave padded LDS.
__global__ __launch_bounds__(256, 4) void attn_k(
    const unsigned short* __restrict__ Q,   // [16][4096][64], pre-scaled
    const unsigned short* __restrict__ Kb,  // [16][4096][64]
    const unsigned short* __restrict__ Vt,  // [16][64][4096]
    const float* __restrict__ l2s,          // [4096] log2(size)
    unsigned short* __restrict__ O)         // [4096][1024] bf16
{
  __shared__ __align__(16) unsigned short Ks[64 * 64];
  __shared__ __align__(16) unsigned short Vs[64 * 64];
  __shared__ __align__(16) unsigned short Ps[4][16 * 72];  // per-wave, +8 pad

  const int tid = threadIdx.x;
  const int wv = tid >> 6, ln = tid & 63;
  const int h = blockIdx.y;
  const int q0 = blockIdx.x * 64;
  const int lrow = ln & 15, lq = ln >> 4;

  short8 qf0, qf1;  // hoisted Q A-fragments (row = lane&15, k contiguous)
  {
    const unsigned short* qp = Q + ((size_t)h * L_SEQ + q0 + wv * 16 + lrow) * HD + lq * 8;
    qf0 = *(const short8*)qp;
    qf1 = *(const short8*)(qp + 32);
  }

  f32x4 o[4] = {};
  float mrun[4], lrun[4];
#pragma unroll
  for (int r = 0; r < 4; ++r) { mrun[r] = -1e30f; lrun[r] = 0.f; }

  const int rstg = wv * 8 + (ln >> 3);
  const int ustg = (ln & 7) ^ (ln >> 3);

  for (int t0 = 0; t0 < L_SEQ; t0 += 64) {
#pragma unroll
    for (int i = 0; i < 2; ++i) {
      int r = i * 32 + rstg;
      GLOAD_LDS16(Kb + ((size_t)h * L_SEQ + t0 + r) * HD + (ustg << 3), Ks + i * 2048 + wv * 512);
      GLOAD_LDS16(Vt + ((size_t)(h * HD + r)) * L_SEQ + t0 + (ustg << 3), Vs + i * 2048 + wv * 512);
    }
    __syncthreads();

    // S = Q K^T  (rows q, cols key)
    f32x4 s[4] = {};
#pragma unroll
    for (int ks = 0; ks < 2; ++ks) {
      short8 qa = ks ? qf1 : qf0;
#pragma unroll
      for (int f = 0; f < 4; ++f) {
        int key = f * 16 + lrow;
        int u = (ks * 4 + lq) ^ (key & 7);
        short8 kb = *(const short8*)(Ks + key * 64 + (u << 3));
        s[f] = __builtin_amdgcn_mfma_f32_16x16x32_bf16(qa, kb, s[f], 0, 0, 0);
      }
    }

    // base-2 logits + log2(size_key)
#pragma unroll
    for (int f = 0; f < 4; ++f) {
      float bias = l2s[t0 + f * 16 + lrow];
#pragma unroll
      for (int r = 0; r < 4; ++r)
        s[f][r] = s[f][r] * LOG2E + bias;
    }

    // online softmax; row r lives in 16-lane group (lanes share lq)
    float alpha[4];
#pragma unroll
    for (int r = 0; r < 4; ++r) {
      float t = fmaxf(fmaxf(s[0][r], s[1][r]), fmaxf(s[2][r], s[3][r]));
      t = fmaxf(t, __shfl_xor(t, 1));
      t = fmaxf(t, __shfl_xor(t, 2));
      t = fmaxf(t, __shfl_xor(t, 4));
      t = fmaxf(t, __shfl_xor(t, 8));
      float mnew = fmaxf(mrun[r], t);
      alpha[r] = __builtin_amdgcn_exp2f(mrun[r] - mnew);
      mrun[r] = mnew;
      float rs = 0.f;
#pragma unroll
      for (int f = 0; f < 4; ++f) {
        float pv = __builtin_amdgcn_exp2f(s[f][r] - mnew);
        s[f][r] = pv;
        rs += pv;
      }
      rs += __shfl_xor(rs, 1);
      rs += __shfl_xor(rs, 2);
      rs += __shfl_xor(rs, 4);
      rs += __shfl_xor(rs, 8);
      lrun[r] = lrun[r] * alpha[r] + rs;
    }
#pragma unroll
    for (int df = 0; df < 4; ++df)
#pragma unroll
      for (int r = 0; r < 4; ++r) o[df][r] *= alpha[r];

    // P -> per-wave LDS (C layout in, A layout out), padded to 72 shorts/row
    unsigned short* pb = &Ps[wv][0];
#pragma unroll
    for (int f = 0; f < 4; ++f)
#pragma unroll
      for (int r = 0; r < 4; ++r)
        pb[(lq * 4 + r) * 72 + f * 16 + lrow] = f2bf(s[f][r]);

    asm volatile("s_waitcnt lgkmcnt(0)" ::: "memory");  // cross-lane LDS dep
    __builtin_amdgcn_sched_barrier(0);

    short8 pa0 = *(const short8*)(pb + lrow * 72 + lq * 8);
    short8 pa1 = *(const short8*)(pb + lrow * 72 + 32 + lq * 8);

    // O += P @ V   (B operand from transposed-V tile: row=d, k=key)
#pragma unroll
    for (int ks = 0; ks < 2; ++ks) {
      short8 pa = ks ? pa1 : pa0;
#pragma unroll
      for (int df = 0; df < 4; ++df) {
        int d = df * 16 + lrow;
        int u = (ks * 4 + lq) ^ (d & 7);
        short8 vb = *(const short8*)(Vs + d * 64 + (u << 3));
        o[df] = __builtin_amdgcn_mfma_f32_16x16x32_bf16(pa, vb, o[df], 0, 0, 0);
      }
    }
    __syncthreads();
  }

  // epilogue: divide by softmax denom, store bf16 [t][h*64+d]
#pragma unroll
  for (int df = 0; df < 4; ++df)
#pragma unroll
    for (int r = 0; r < 4; ++r) {
      int q = q0 + wv * 16 + lq * 4 + r;
      O[(size_t)q * EMBED + h * HD + df * 16 + lrow] = f2bf(o[df][r] / lrun[r]);
    }
}

// ---------------- metric = mean over heads of K ----------------
__global__ void metric_k(const unsigned short* __restrict__ Kb, float* __restrict__ out) {
  int idx = blockIdx.x * blockDim.x + threadIdx.x;  // 4096*64
  int t = idx >> 6, d = idx & 63;
  float s = 0.f;
#pragma unroll
  for (int h = 0; h < HEADS; ++h)
    s += bf2f(Kb[((size_t)h * L_SEQ + t) * HD + d]);
  out[idx] = s * (1.0f / 16.0f);
}

extern "C" void kernel_launch(void* const* d_in, const int* in_sizes, int n_in,
                              void* d_out, int out_size, void* d_ws, size_t ws_size,
                              hipStream_t stream) {
  const float* hs = (const float*)d_in[0];
  const float* sz = (const float*)d_in[1];
  const float* wq = (const float*)d_in[2];
  const float* bq = (const float*)d_in[3];
  const float* wk = (const float*)d_in[4];
  const float* bk = (const float*)d_in[5];
  const float* wv = (const float*)d_in[6];
  const float* bv = (const float*)d_in[7];
  const float* wo = (const float*)d_in[8];
  const float* bo = (const float*)d_in[9];

  char* ws = (char*)d_ws;                                     // layout (48MB+16KB):
  unsigned short* hs_b = (unsigned short*)(ws);               // [4096][1024] bf16
  unsigned short* wq_b = (unsigned short*)(ws + (8u << 20));  // 4 weights bf16
  unsigned short* wk_b = wq_b + (1u << 20);
  unsigned short* wv_b = wq_b + (2u << 20);
  unsigned short* wo_b = wq_b + (3u << 20);
  unsigned short* q_b  = (unsigned short*)(ws + (16u << 20)); // [16][4096][64]
  unsigned short* k_b  = (unsigned short*)(ws + (24u << 20)); // [16][4096][64]
  unsigned short* vt_b = (unsigned short*)(ws + (32u << 20)); // [16][64][4096]
  unsigned short* at_b = (unsigned short*)(ws + (40u << 20)); // [4096][1024]
  float* l2s = (float*)(ws + (48u << 20));                    // [4096]

  float* outp = (float*)d_out;
  float* metricp = outp + (size_t)L_SEQ * EMBED;

  cast_bf16_k<<<L_SEQ * EMBED / 8 / 256, 256, 0, stream>>>(hs, hs_b, L_SEQ * EMBED / 8);
  cast_bf16_k<<<EMBED * EMBED / 8 / 256, 256, 0, stream>>>(wq, wq_b, EMBED * EMBED / 8);
  cast_bf16_k<<<EMBED * EMBED / 8 / 256, 256, 0, stream>>>(wk, wk_b, EMBED * EMBED / 8);
  cast_bf16_k<<<EMBED * EMBED / 8 / 256, 256, 0, stream>>>(wv, wv_b, EMBED * EMBED / 8);
  cast_bf16_k<<<EMBED * EMBED / 8 / 256, 256, 0, stream>>>(wo, wo_b, EMBED * EMBED / 8);
  l2size_k<<<L_SEQ / 256, 256, 0, stream>>>(sz, l2s, L_SEQ);

  GemmArgs aq{wq_b, bq, (void*)q_b, 0};
  GemmArgs ak{wk_b, bk, (void*)k_b, 1};
  GemmArgs av{wv_b, bv, (void*)vt_b, 2};
  gemm_bt_k<<<dim3(256, 3), 256, 0, stream>>>(hs_b, aq, ak, av);   // fused QKV

  metric_k<<<L_SEQ * HD / 256, 256, 0, stream>>>(k_b, metricp);

  attn_k<<<dim3(64, 16), 256, 0, stream>>>(q_b, k_b, vt_b, l2s, at_b);

  GemmArgs ao{wo_b, bo, (void*)outp, 3};
  gemm_bt_k<<<dim3(256, 1), 256, 0, stream>>>(at_b, ao, ao, ao);   // O projection
}